// Round 1
// baseline (1071.906 us; speedup 1.0000x reference)
//
#include <hip/hip_runtime.h>

#define N_M 100000
#define N_A 20000
#define E_C 1600000
#define E_K 800000

// ---- float <-> monotone unsigned key (for atomic max over floats) ----
__device__ __forceinline__ unsigned fkey(float f) {
    unsigned u = __float_as_uint(f);
    return (u & 0x80000000u) ? ~u : (u | 0x80000000u);
}
__device__ __forceinline__ float fdecode(unsigned k) {
    unsigned u = (k & 0x80000000u) ? (k ^ 0x80000000u) : ~k;
    return __uint_as_float(u);
}

// ---- scatter-add: agg[dst] += x[src] * w, D features per edge ----
template <int D>
__global__ __launch_bounds__(256) void scatter_add_edges(
    const float* __restrict__ x, const float* __restrict__ w,
    const int* __restrict__ src, const int* __restrict__ dst,
    float* __restrict__ agg, int nE) {
    int t = blockIdx.x * blockDim.x + threadIdx.x;
    int e = t / D;
    int f = t % D;
    if (e >= nE) return;
    int s = src[e], d = dst[e];
    float v = x[(size_t)s * D + f] * w[e];
    atomicAdd(&agg[(size_t)d * D + f], v);
}

// ---- scatter-max: aggk[dst] = max(aggk[dst], key(x[src]*w)) ----
template <int D>
__global__ __launch_bounds__(256) void scatter_max_edges(
    const float* __restrict__ x, const float* __restrict__ w,
    const int* __restrict__ src, const int* __restrict__ dst,
    unsigned* __restrict__ agg, int nE) {
    int t = blockIdx.x * blockDim.x + threadIdx.x;
    int e = t / D;
    int f = t % D;
    if (e >= nE) return;
    int s = src[e], d = dst[e];
    float v = x[(size_t)s * D + f] * w[e];
    atomicMax(&agg[(size_t)d * D + f], fkey(v));
}

// ---- decode keys in place; empty segments (key==0 -> NaN) -> 0 ----
__global__ __launch_bounds__(256) void decode_max(unsigned* __restrict__ agg, int n) {
    int i = blockIdx.x * blockDim.x + threadIdx.x;
    if (i >= n) return;
    float f = fdecode(agg[i]);
    unsigned u = __float_as_uint(f);
    if (((u >> 23) & 0xffu) == 0xffu) f = 0.0f;  // inf/NaN -> 0
    ((float*)agg)[i] = f;
}

// ---- dual GEMM + bias + leaky: out = leaky(A1@W1 + A2@W2 + b) ----
// A1: [M,K1], A2: [M,K2], W1: [K1,N], W2: [K2,N] (row-major)
__global__ __launch_bounds__(256) void dual_gemm_leaky(
    const float* __restrict__ A1, const float* __restrict__ A2,
    const float* __restrict__ W1, const float* __restrict__ W2,
    const float* __restrict__ bias, float* __restrict__ out,
    int M, int N, int K1, int K2) {
    constexpr int BM = 64, BN = 64, BK = 16;
    __shared__ float sA[BK][BM];
    __shared__ float sB[BK][BN];
    const int tid = threadIdx.x;
    const int bm0 = blockIdx.y * BM;
    const int bn0 = blockIdx.x * BN;
    const int K = K1 + K2;
    float acc[4][4] = {};
    const int ty = tid >> 4, tx = tid & 15;

    for (int k0 = 0; k0 < K; k0 += BK) {
        // load A tile (BM x BK = 1024 elems, 4/thread)
        #pragma unroll
        for (int i = 0; i < (BM * BK) / 256; ++i) {
            int idx = tid + i * 256;
            int m = idx & (BM - 1);
            int k = idx >> 6;
            int gm = bm0 + m, gk = k0 + k;
            float v = 0.0f;
            if (gm < M)
                v = (gk < K1) ? A1[(size_t)gm * K1 + gk]
                              : A2[(size_t)gm * K2 + (gk - K1)];
            sA[k][m] = v;
        }
        // load B tile (BK x BN)
        #pragma unroll
        for (int i = 0; i < (BK * BN) / 256; ++i) {
            int idx = tid + i * 256;
            int n = idx & (BN - 1);
            int k = idx >> 6;
            int gk = k0 + k;
            float v = (gk < K1) ? W1[(size_t)gk * N + bn0 + n]
                                : W2[(size_t)(gk - K1) * N + bn0 + n];
            sB[k][n] = v;
        }
        __syncthreads();
        #pragma unroll
        for (int kk = 0; kk < BK; ++kk) {
            float a[4], b[4];
            #pragma unroll
            for (int i = 0; i < 4; ++i) a[i] = sA[kk][ty * 4 + i];
            #pragma unroll
            for (int j = 0; j < 4; ++j) b[j] = sB[kk][tx * 4 + j];
            #pragma unroll
            for (int i = 0; i < 4; ++i)
                #pragma unroll
                for (int j = 0; j < 4; ++j)
                    acc[i][j] = fmaf(a[i], b[j], acc[i][j]);
        }
        __syncthreads();
    }
    // epilogue: bias + leaky relu
    #pragma unroll
    for (int i = 0; i < 4; ++i) {
        int gm = bm0 + ty * 4 + i;
        if (gm >= M) continue;
        #pragma unroll
        for (int j = 0; j < 4; ++j) {
            int gn = bn0 + tx * 4 + j;
            float v = acc[i][j] + bias[gn];
            out[(size_t)gm * N + gn] = (v > 0.0f) ? v : 0.01f * v;
        }
    }
}

extern "C" void kernel_launch(void* const* d_in, const int* in_sizes, int n_in,
                              void* d_out, int out_size, void* d_ws, size_t ws_size,
                              hipStream_t stream) {
    const float* x_metric = (const float*)d_in[0];
    const float* x_alert  = (const float*)d_in[1];
    const float* w_corr   = (const float*)d_in[2];
    const float* w_cause  = (const float*)d_in[3];
    const int* src_corr   = (const int*)d_in[4];
    const int* dst_corr   = (const int*)d_in[5];
    const int* src_cause  = (const int*)d_in[6];
    const int* dst_cause  = (const int*)d_in[7];
    const float* Wr_c0 = (const float*)d_in[8];
    const float* br_c0 = (const float*)d_in[9];
    const float* Wo_c0 = (const float*)d_in[10];
    const float* Wr_k0 = (const float*)d_in[11];
    const float* br_k0 = (const float*)d_in[12];
    const float* Wo_k0 = (const float*)d_in[13];
    // layer-1 corr weights (d_in[14..16]) are dead: new_m of layer 1 is unused.
    const float* Wr_k1 = (const float*)d_in[17];
    const float* br_k1 = (const float*)d_in[18];
    const float* Wo_k1 = (const float*)d_in[19];

    // workspace layout (floats)
    float* ws   = (float*)d_ws;
    float* xm0  = ws;                              // N_M x 128
    float* xa0  = xm0 + (size_t)N_M * 128;         // N_A x 128
    float* aggm = xa0 + (size_t)N_A * 128;         // N_M x 64
    unsigned* aggk = (unsigned*)(aggm + (size_t)N_M * 64); // N_A x 128 (keys/floats)

    // ---- layer 0 ----
    // zero agg_sum (metric, 64f) and agg_max keys (alert, 64f) in one memset (contiguous)
    hipMemsetAsync(aggm, 0, ((size_t)N_M * 64 + (size_t)N_A * 64) * sizeof(float), stream);

    {   // corr: segment_sum over 1.6M edges, 64 features
        int blocks = (int)(((size_t)E_C * 64 + 255) / 256);
        scatter_add_edges<64><<<blocks, 256, 0, stream>>>(x_metric, w_corr, src_corr, dst_corr, aggm, E_C);
    }
    {   // cause: segment_max over 0.8M edges, 64 features
        int blocks = (int)(((size_t)E_K * 64 + 255) / 256);
        scatter_max_edges<64><<<blocks, 256, 0, stream>>>(x_metric, w_cause, src_cause, dst_cause, aggk, E_K);
        int n = N_A * 64;
        decode_max<<<(n + 255) / 256, 256, 0, stream>>>(aggk, n);
    }
    {   // new_m = leaky(aggm@Wr_c0 + x_metric@Wo_c0 + br_c0)  -> xm0 [N_M,128]
        dim3 grid(128 / 64, (N_M + 63) / 64);
        dual_gemm_leaky<<<grid, 256, 0, stream>>>(aggm, x_metric, Wr_c0, Wo_c0, br_c0, xm0, N_M, 128, 64, 64);
    }
    {   // new_a = leaky(aggk@Wr_k0 + x_alert@Wo_k0 + br_k0)  -> xa0 [N_A,128]
        dim3 grid(128 / 64, (N_A + 63) / 64);
        dual_gemm_leaky<<<grid, 256, 0, stream>>>((const float*)aggk, x_alert, Wr_k0, Wo_k0, br_k0, xa0, N_A, 128, 64, 64);
    }

    // ---- layer 1 (metric update is dead code; only alert path) ----
    hipMemsetAsync(aggk, 0, (size_t)N_A * 128 * sizeof(unsigned), stream);
    {   // cause: segment_max over 0.8M edges, 128 features, x = xm0
        int blocks = (int)(((size_t)E_K * 128 + 255) / 256);
        scatter_max_edges<128><<<blocks, 256, 0, stream>>>(xm0, w_cause, src_cause, dst_cause, aggk, E_K);
        int n = N_A * 128;
        decode_max<<<(n + 255) / 256, 256, 0, stream>>>(aggk, n);
    }
    {   // out = leaky(aggk@Wr_k1 + xa0@Wo_k1 + br_k1)  -> [N_A,256]
        dim3 grid(256 / 64, (N_A + 63) / 64);
        dual_gemm_leaky<<<grid, 256, 0, stream>>>((const float*)aggk, xa0, Wr_k1, Wo_k1, br_k1, (float*)d_out, N_A, 256, 128, 128);
    }
}

// Round 3
// 944.791 us; speedup vs baseline: 1.1345x; 1.1345x over previous
//
#include <hip/hip_runtime.h>

#define N_M 100000
#define N_A 20000
#define E_C 1600000
#define E_K 800000

// =================== CSR build (per call; ws is re-poisoned) ===================

__global__ __launch_bounds__(256) void hist_kernel(const int* __restrict__ dst,
                                                   int* __restrict__ deg, int nE) {
    int e = blockIdx.x * 256 + threadIdx.x;
    if (e < nE) atomicAdd(&deg[dst[e]], 1);
}

// Single-block chunked exclusive scan. deg may alias cursor (each element is
// read exactly once before being written by the same thread).
__global__ __launch_bounds__(1024) void scan_kernel(const int* __restrict__ deg,
                                                    int* __restrict__ rowptr,
                                                    int* __restrict__ cursor, int n) {
    __shared__ int buf[1024];
    __shared__ int carry_s;
    int tid = threadIdx.x;
    if (tid == 0) carry_s = 0;
    __syncthreads();
    for (int base = 0; base < n; base += 4096) {
        int v[4]; int idx[4]; int lsum = 0;
        #pragma unroll
        for (int k = 0; k < 4; ++k) {
            idx[k] = base + tid * 4 + k;
            v[k] = (idx[k] < n) ? deg[idx[k]] : 0;
            lsum += v[k];
        }
        buf[tid] = lsum;
        __syncthreads();
        for (int off = 1; off < 1024; off <<= 1) {
            int t = (tid >= off) ? buf[tid - off] : 0;
            __syncthreads();
            buf[tid] += t;
            __syncthreads();
        }
        int excl = buf[tid] - lsum + carry_s;   // carry_s stable: last write ≥1 barrier ago
        #pragma unroll
        for (int k = 0; k < 4; ++k) {
            if (idx[k] < n) { rowptr[idx[k]] = excl; cursor[idx[k]] = excl; }
            excl += v[k];
        }
        __syncthreads();
        if (tid == 1023) carry_s += buf[1023];
        __syncthreads();
    }
    if (tid == 0) rowptr[n] = carry_s;
}

__global__ __launch_bounds__(256) void fill_kernel(const int* __restrict__ dst,
                                                   int* __restrict__ cursor,
                                                   int* __restrict__ eids, int nE) {
    int e = blockIdx.x * 256 + threadIdx.x;
    if (e < nE) {
        int p = atomicAdd(&cursor[dst[e]], 1);
        eids[p] = e;
    }
}

// =================== gather-side aggregations (no atomics) ===================
// One wave (64 lanes) per destination node; lane = feature (D=64) or
// feature-pair (D=128). Edge loop unrolled for memory-level parallelism.

__global__ __launch_bounds__(256) void agg_sum_d64(
    const float* __restrict__ x, const float* __restrict__ w, const int* __restrict__ src,
    const int* __restrict__ rowptr, const int* __restrict__ eids,
    float* __restrict__ out, int n) {
    int gw = blockIdx.x * 4 + (threadIdx.x >> 6);
    int lane = threadIdx.x & 63;
    if (gw >= n) return;
    int j = rowptr[gw], end = rowptr[gw + 1];
    float acc = 0.f;
    for (; j + 4 <= end; j += 4) {
        int e0 = eids[j], e1 = eids[j + 1], e2 = eids[j + 2], e3 = eids[j + 3];
        int s0 = src[e0], s1 = src[e1], s2 = src[e2], s3 = src[e3];
        float w0 = w[e0], w1 = w[e1], w2 = w[e2], w3 = w[e3];
        float v0 = x[(size_t)s0 * 64 + lane];
        float v1 = x[(size_t)s1 * 64 + lane];
        float v2 = x[(size_t)s2 * 64 + lane];
        float v3 = x[(size_t)s3 * 64 + lane];
        acc = fmaf(v0, w0, acc); acc = fmaf(v1, w1, acc);
        acc = fmaf(v2, w2, acc); acc = fmaf(v3, w3, acc);
    }
    for (; j < end; ++j) {
        int e = eids[j];
        acc = fmaf(x[(size_t)src[e] * 64 + lane], w[e], acc);
    }
    out[(size_t)gw * 64 + lane] = acc;
}

__global__ __launch_bounds__(256) void agg_max_d64(
    const float* __restrict__ x, const float* __restrict__ w, const int* __restrict__ src,
    const int* __restrict__ rowptr, const int* __restrict__ eids,
    float* __restrict__ out, int n) {
    int gw = blockIdx.x * 4 + (threadIdx.x >> 6);
    int lane = threadIdx.x & 63;
    if (gw >= n) return;
    int beg = rowptr[gw], end = rowptr[gw + 1];
    float acc = -INFINITY;
    int j = beg;
    for (; j + 4 <= end; j += 4) {
        int e0 = eids[j], e1 = eids[j + 1], e2 = eids[j + 2], e3 = eids[j + 3];
        int s0 = src[e0], s1 = src[e1], s2 = src[e2], s3 = src[e3];
        float w0 = w[e0], w1 = w[e1], w2 = w[e2], w3 = w[e3];
        float v0 = x[(size_t)s0 * 64 + lane];
        float v1 = x[(size_t)s1 * 64 + lane];
        float v2 = x[(size_t)s2 * 64 + lane];
        float v3 = x[(size_t)s3 * 64 + lane];
        acc = fmaxf(acc, v0 * w0); acc = fmaxf(acc, v1 * w1);
        acc = fmaxf(acc, v2 * w2); acc = fmaxf(acc, v3 * w3);
    }
    for (; j < end; ++j) {
        int e = eids[j];
        acc = fmaxf(acc, x[(size_t)src[e] * 64 + lane] * w[e]);
    }
    if (beg == end) acc = 0.f;   // torch_scatter empty-segment convention
    out[(size_t)gw * 64 + lane] = acc;
}

__global__ __launch_bounds__(256) void agg_max_d128(
    const float* __restrict__ x, const float* __restrict__ w, const int* __restrict__ src,
    const int* __restrict__ rowptr, const int* __restrict__ eids,
    float* __restrict__ out, int n) {
    int gw = blockIdx.x * 4 + (threadIdx.x >> 6);
    int lane = threadIdx.x & 63;
    if (gw >= n) return;
    int beg = rowptr[gw], end = rowptr[gw + 1];
    float ax = -INFINITY, ay = -INFINITY;
    int j = beg;
    for (; j + 2 <= end; j += 2) {
        int e0 = eids[j], e1 = eids[j + 1];
        int s0 = src[e0], s1 = src[e1];
        float w0 = w[e0], w1 = w[e1];
        float2 v0 = ((const float2*)(x + (size_t)s0 * 128))[lane];
        float2 v1 = ((const float2*)(x + (size_t)s1 * 128))[lane];
        ax = fmaxf(ax, v0.x * w0); ay = fmaxf(ay, v0.y * w0);
        ax = fmaxf(ax, v1.x * w1); ay = fmaxf(ay, v1.y * w1);
    }
    for (; j < end; ++j) {
        int e = eids[j];
        float ww = w[e];
        float2 v = ((const float2*)(x + (size_t)src[e] * 128))[lane];
        ax = fmaxf(ax, v.x * ww); ay = fmaxf(ay, v.y * ww);
    }
    if (beg == end) { ax = 0.f; ay = 0.f; }
    ((float2*)(out + (size_t)gw * 128))[lane] = make_float2(ax, ay);
}

// ---- dual GEMM + bias + leaky: out = leaky(A1@W1 + A2@W2 + b) ----
__global__ __launch_bounds__(256) void dual_gemm_leaky(
    const float* __restrict__ A1, const float* __restrict__ A2,
    const float* __restrict__ W1, const float* __restrict__ W2,
    const float* __restrict__ bias, float* __restrict__ out,
    int M, int N, int K1, int K2) {
    constexpr int BM = 64, BN = 64, BK = 16;
    __shared__ float sA[BK][BM];
    __shared__ float sB[BK][BN];
    const int tid = threadIdx.x;
    const int bm0 = blockIdx.y * BM;
    const int bn0 = blockIdx.x * BN;
    const int K = K1 + K2;
    float acc[4][4] = {};
    const int ty = tid >> 4, tx = tid & 15;

    for (int k0 = 0; k0 < K; k0 += BK) {
        #pragma unroll
        for (int i = 0; i < (BM * BK) / 256; ++i) {
            int idx = tid + i * 256;
            int m = idx & (BM - 1);
            int k = idx >> 6;
            int gm = bm0 + m, gk = k0 + k;
            float v = 0.0f;
            if (gm < M)
                v = (gk < K1) ? A1[(size_t)gm * K1 + gk]
                              : A2[(size_t)gm * K2 + (gk - K1)];
            sA[k][m] = v;
        }
        #pragma unroll
        for (int i = 0; i < (BK * BN) / 256; ++i) {
            int idx = tid + i * 256;
            int n = idx & (BN - 1);
            int k = idx >> 6;
            int gk = k0 + k;
            float v = (gk < K1) ? W1[(size_t)gk * N + bn0 + n]
                                : W2[(size_t)(gk - K1) * N + bn0 + n];
            sB[k][n] = v;
        }
        __syncthreads();
        #pragma unroll
        for (int kk = 0; kk < BK; ++kk) {
            float a[4], b[4];
            #pragma unroll
            for (int i = 0; i < 4; ++i) a[i] = sA[kk][ty * 4 + i];
            #pragma unroll
            for (int j = 0; j < 4; ++j) b[j] = sB[kk][tx * 4 + j];
            #pragma unroll
            for (int i = 0; i < 4; ++i)
                #pragma unroll
                for (int j = 0; j < 4; ++j)
                    acc[i][j] = fmaf(a[i], b[j], acc[i][j]);
        }
        __syncthreads();
    }
    #pragma unroll
    for (int i = 0; i < 4; ++i) {
        int gm = bm0 + ty * 4 + i;
        if (gm >= M) continue;
        #pragma unroll
        for (int j = 0; j < 4; ++j) {
            int gn = bn0 + tx * 4 + j;
            float v = acc[i][j] + bias[gn];
            out[(size_t)gm * N + gn] = (v > 0.0f) ? v : 0.01f * v;
        }
    }
}

extern "C" void kernel_launch(void* const* d_in, const int* in_sizes, int n_in,
                              void* d_out, int out_size, void* d_ws, size_t ws_size,
                              hipStream_t stream) {
    const float* x_metric = (const float*)d_in[0];
    const float* x_alert  = (const float*)d_in[1];
    const float* w_corr   = (const float*)d_in[2];
    const float* w_cause  = (const float*)d_in[3];
    const int* src_corr   = (const int*)d_in[4];
    const int* dst_corr   = (const int*)d_in[5];
    const int* src_cause  = (const int*)d_in[6];
    const int* dst_cause  = (const int*)d_in[7];
    const float* Wr_c0 = (const float*)d_in[8];
    const float* br_c0 = (const float*)d_in[9];
    const float* Wo_c0 = (const float*)d_in[10];
    const float* Wr_k0 = (const float*)d_in[11];
    const float* br_k0 = (const float*)d_in[12];
    const float* Wo_k0 = (const float*)d_in[13];
    // d_in[14..16] (layer-1 corr weights) are dead: layer-1 metric update unused.
    const float* Wr_k1 = (const float*)d_in[17];
    const float* br_k1 = (const float*)d_in[18];
    const float* Wo_k1 = (const float*)d_in[19];

    // ---- workspace layout (4-byte elements), total 95.5 MB, aliased ----
    float* ws = (float*)d_ws;
    float* xm0 = ws;                                  // [0 .. 12.8M) N_M x 128
    // region2 (2.56M elems): corr CSR first, then reused by xa0
    int*   corr_rowptr = (int*)(ws + 12800000);       // N_M+1
    int*   corr_cursor = corr_rowptr + 100032;        // N_M
    int*   corr_eids   = corr_cursor + 100032;        // E_C
    float* xa0         = (float*)corr_rowptr;         // N_A x 128 (after corr CSR dead)
    float* aggm  = ws + 12800000 + 2560000;           // N_M x 64; later aliased by aggk1
    float* aggk0 = aggm + 6400000;                    // N_A x 64
    float* aggk1 = aggm;                              // N_A x 128 (after aggm dead)
    int* cause_rowptr = (int*)(aggk0 + 1280000);      // N_A+1
    int* cause_cursor = cause_rowptr + 20032;         // N_A
    int* cause_eids   = cause_cursor + 20032;         // E_K

    // ---- build CSR (dst-sorted) for both edge types ----
    hipMemsetAsync(corr_cursor, 0, (size_t)N_M * 4, stream);
    hipMemsetAsync(cause_cursor, 0, (size_t)N_A * 4, stream);
    hist_kernel<<<(E_C + 255) / 256, 256, 0, stream>>>(dst_corr, corr_cursor, E_C);
    hist_kernel<<<(E_K + 255) / 256, 256, 0, stream>>>(dst_cause, cause_cursor, E_K);
    scan_kernel<<<1, 1024, 0, stream>>>(corr_cursor, corr_rowptr, corr_cursor, N_M);
    scan_kernel<<<1, 1024, 0, stream>>>(cause_cursor, cause_rowptr, cause_cursor, N_A);
    fill_kernel<<<(E_C + 255) / 256, 256, 0, stream>>>(dst_corr, corr_cursor, corr_eids, E_C);
    fill_kernel<<<(E_K + 255) / 256, 256, 0, stream>>>(dst_cause, cause_cursor, cause_eids, E_K);

    // ---- layer 0 aggregations (gather, no atomics, decode fused) ----
    agg_sum_d64<<<(N_M + 3) / 4, 256, 0, stream>>>(x_metric, w_corr, src_corr,
                                                   corr_rowptr, corr_eids, aggm, N_M);
    agg_max_d64<<<(N_A + 3) / 4, 256, 0, stream>>>(x_metric, w_cause, src_cause,
                                                   cause_rowptr, cause_eids, aggk0, N_A);

    // ---- layer 0 GEMMs ----
    {   // new_m = leaky(aggm@Wr_c0 + x_metric@Wo_c0 + br_c0) -> xm0 [N_M,128]
        dim3 grid(128 / 64, (N_M + 63) / 64);
        dual_gemm_leaky<<<grid, 256, 0, stream>>>(aggm, x_metric, Wr_c0, Wo_c0, br_c0,
                                                  xm0, N_M, 128, 64, 64);
    }
    {   // new_a = leaky(aggk0@Wr_k0 + x_alert@Wo_k0 + br_k0) -> xa0 [N_A,128]
        // (clobbers corr CSR region — dead by now)
        dim3 grid(128 / 64, (N_A + 63) / 64);
        dual_gemm_leaky<<<grid, 256, 0, stream>>>(aggk0, x_alert, Wr_k0, Wo_k0, br_k0,
                                                  xa0, N_A, 128, 64, 64);
    }

    // ---- layer 1 (alert path only; metric update is dead code) ----
    agg_max_d128<<<(N_A + 3) / 4, 256, 0, stream>>>(xm0, w_cause, src_cause,
                                                    cause_rowptr, cause_eids, aggk1, N_A);
    {   // out = leaky(aggk1@Wr_k1 + xa0@Wo_k1 + br_k1) -> [N_A,256]
        dim3 grid(256 / 64, (N_A + 63) / 64);
        dual_gemm_leaky<<<grid, 256, 0, stream>>>(aggk1, xa0, Wr_k1, Wo_k1, br_k1,
                                                  (float*)d_out, N_A, 256, 128, 128);
    }
}

// Round 4
// 719.177 us; speedup vs baseline: 1.4905x; 1.3137x over previous
//
#include <hip/hip_runtime.h>

#define N_M 100000
#define N_A 20000
#define E_C 1600000
#define E_K 800000
#define CH 2048           // edges per chunk (256 threads x 8)
#define NXCD 8

// =================== XCD-partitioned CSR build ===================
// block b: chunk = b>>3, dst-range = b&7. Consecutive blockIdx round-robin
// across XCDs, so each dst-range's cursor atomics + CSR writes stay in ONE
// XCD's L2 -> no cross-XCD line ping-pong, full-line writebacks.

__global__ __launch_bounds__(256) void hist_part(const int* __restrict__ dst,
                                                 int* __restrict__ deg,
                                                 int nE, int nodes_per_part) {
    int chunk = blockIdx.x >> 3, part = blockIdx.x & 7;
    int lo = part * nodes_per_part, hi = lo + nodes_per_part;
    int base = chunk * CH + threadIdx.x;
    #pragma unroll
    for (int k = 0; k < 8; ++k) {
        int e = base + k * 256;
        if (e < nE) {
            int d = dst[e];
            if (d >= lo && d < hi) atomicAdd(&deg[d], 1);
        }
    }
}

__global__ __launch_bounds__(256) void fill_eids_part(const int* __restrict__ dst,
                                                      int* __restrict__ cursor,
                                                      int* __restrict__ eids,
                                                      int nE, int nodes_per_part) {
    int chunk = blockIdx.x >> 3, part = blockIdx.x & 7;
    int lo = part * nodes_per_part, hi = lo + nodes_per_part;
    int base = chunk * CH + threadIdx.x;
    #pragma unroll
    for (int k = 0; k < 8; ++k) {
        int e = base + k * 256;
        if (e < nE) {
            int d = dst[e];
            if (d >= lo && d < hi) {
                int p = atomicAdd(&cursor[d], 1);
                eids[p] = e;
            }
        }
    }
}

__global__ __launch_bounds__(256) void fill_pay_part(const int* __restrict__ dst,
                                                     const int* __restrict__ src,
                                                     const float* __restrict__ w,
                                                     int* __restrict__ cursor,
                                                     int* __restrict__ csr_src,
                                                     float* __restrict__ csr_w,
                                                     int nE, int nodes_per_part) {
    int chunk = blockIdx.x >> 3, part = blockIdx.x & 7;
    int lo = part * nodes_per_part, hi = lo + nodes_per_part;
    int base = chunk * CH + threadIdx.x;
    #pragma unroll
    for (int k = 0; k < 8; ++k) {
        int e = base + k * 256;
        if (e < nE) {
            int d = dst[e];
            if (d >= lo && d < hi) {
                int p = atomicAdd(&cursor[d], 1);
                csr_src[p] = src[e];
                csr_w[p]   = w[e];
            }
        }
    }
}

// =================== multi-block exclusive scan (3 phases) ===================

__global__ __launch_bounds__(256) void scan_p1(const int* __restrict__ deg,
                                               int* __restrict__ partial, int n) {
    __shared__ int red[256];
    int base = blockIdx.x * CH + threadIdx.x;
    int s = 0;
    #pragma unroll
    for (int k = 0; k < 8; ++k) { int i = base + k * 256; if (i < n) s += deg[i]; }
    red[threadIdx.x] = s; __syncthreads();
    for (int off = 128; off > 0; off >>= 1) {
        if (threadIdx.x < off) red[threadIdx.x] += red[threadIdx.x + off];
        __syncthreads();
    }
    if (threadIdx.x == 0) partial[blockIdx.x] = red[0];
}

// one wave; P <= 64
__global__ __launch_bounds__(64) void scan_p2(int* __restrict__ partial,
                                              int* __restrict__ rowptr_end, int P) {
    int lane = threadIdx.x;
    int v = (lane < P) ? partial[lane] : 0;
    int incl = v;
    for (int off = 1; off < 64; off <<= 1) {
        int t = __shfl_up(incl, off);
        if (lane >= off) incl += t;
    }
    if (lane < P) partial[lane] = incl - v;   // exclusive
    if (lane == 63) *rowptr_end = incl;       // total
}

// deg may alias cursor: each element read/written by the same thread only.
__global__ __launch_bounds__(256) void scan_p3(const int* __restrict__ deg,
                                               const int* __restrict__ partial,
                                               int* __restrict__ rowptr,
                                               int* __restrict__ cursor, int n) {
    __shared__ int buf[256];
    int base = blockIdx.x * CH;
    int v[8]; int lsum = 0;
    #pragma unroll
    for (int k = 0; k < 8; ++k) {
        int i = base + threadIdx.x * 8 + k;
        v[k] = (i < n) ? deg[i] : 0; lsum += v[k];
    }
    buf[threadIdx.x] = lsum; __syncthreads();
    for (int off = 1; off < 256; off <<= 1) {
        int t = (threadIdx.x >= off) ? buf[threadIdx.x - off] : 0;
        __syncthreads(); buf[threadIdx.x] += t; __syncthreads();
    }
    int excl = buf[threadIdx.x] - lsum + partial[blockIdx.x];
    #pragma unroll
    for (int k = 0; k < 8; ++k) {
        int i = base + threadIdx.x * 8 + k;
        if (i < n) { rowptr[i] = excl; cursor[i] = excl; }
        excl += v[k];
    }
}

// =================== gather-side aggregations (no atomics) ===================

__global__ __launch_bounds__(256) void agg_sum_d64(
    const float* __restrict__ x, const float* __restrict__ w, const int* __restrict__ src,
    const int* __restrict__ rowptr, const int* __restrict__ eids,
    float* __restrict__ out, int n) {
    int gw = blockIdx.x * 4 + (threadIdx.x >> 6);
    int lane = threadIdx.x & 63;
    if (gw >= n) return;
    int j = rowptr[gw], end = rowptr[gw + 1];
    float acc = 0.f;
    for (; j + 4 <= end; j += 4) {
        int e0 = eids[j], e1 = eids[j + 1], e2 = eids[j + 2], e3 = eids[j + 3];
        int s0 = src[e0], s1 = src[e1], s2 = src[e2], s3 = src[e3];
        float w0 = w[e0], w1 = w[e1], w2 = w[e2], w3 = w[e3];
        float v0 = x[(size_t)s0 * 64 + lane];
        float v1 = x[(size_t)s1 * 64 + lane];
        float v2 = x[(size_t)s2 * 64 + lane];
        float v3 = x[(size_t)s3 * 64 + lane];
        acc = fmaf(v0, w0, acc); acc = fmaf(v1, w1, acc);
        acc = fmaf(v2, w2, acc); acc = fmaf(v3, w3, acc);
    }
    for (; j < end; ++j) {
        int e = eids[j];
        acc = fmaf(x[(size_t)src[e] * 64 + lane], w[e], acc);
    }
    out[(size_t)gw * 64 + lane] = acc;
}

__global__ __launch_bounds__(256) void agg_max_d64_p(
    const float* __restrict__ x, const int* __restrict__ csr_src,
    const float* __restrict__ csr_w, const int* __restrict__ rowptr,
    float* __restrict__ out, int n) {
    int gw = blockIdx.x * 4 + (threadIdx.x >> 6);
    int lane = threadIdx.x & 63;
    if (gw >= n) return;
    int beg = rowptr[gw], end = rowptr[gw + 1];
    float acc = -INFINITY;
    int j = beg;
    for (; j + 4 <= end; j += 4) {
        int s0 = csr_src[j], s1 = csr_src[j + 1], s2 = csr_src[j + 2], s3 = csr_src[j + 3];
        float w0 = csr_w[j], w1 = csr_w[j + 1], w2 = csr_w[j + 2], w3 = csr_w[j + 3];
        float v0 = x[(size_t)s0 * 64 + lane];
        float v1 = x[(size_t)s1 * 64 + lane];
        float v2 = x[(size_t)s2 * 64 + lane];
        float v3 = x[(size_t)s3 * 64 + lane];
        acc = fmaxf(acc, v0 * w0); acc = fmaxf(acc, v1 * w1);
        acc = fmaxf(acc, v2 * w2); acc = fmaxf(acc, v3 * w3);
    }
    for (; j < end; ++j)
        acc = fmaxf(acc, x[(size_t)csr_src[j] * 64 + lane] * csr_w[j]);
    if (beg == end) acc = 0.f;   // torch_scatter empty-segment convention
    out[(size_t)gw * 64 + lane] = acc;
}

__global__ __launch_bounds__(256) void agg_max_d128_p(
    const float* __restrict__ x, const int* __restrict__ csr_src,
    const float* __restrict__ csr_w, const int* __restrict__ rowptr,
    float* __restrict__ out, int n) {
    int gw = blockIdx.x * 4 + (threadIdx.x >> 6);
    int lane = threadIdx.x & 63;
    if (gw >= n) return;
    int beg = rowptr[gw], end = rowptr[gw + 1];
    float ax = -INFINITY, ay = -INFINITY;
    int j = beg;
    for (; j + 2 <= end; j += 2) {
        int s0 = csr_src[j], s1 = csr_src[j + 1];
        float w0 = csr_w[j], w1 = csr_w[j + 1];
        float2 v0 = ((const float2*)(x + (size_t)s0 * 128))[lane];
        float2 v1 = ((const float2*)(x + (size_t)s1 * 128))[lane];
        ax = fmaxf(ax, v0.x * w0); ay = fmaxf(ay, v0.y * w0);
        ax = fmaxf(ax, v1.x * w1); ay = fmaxf(ay, v1.y * w1);
    }
    for (; j < end; ++j) {
        float ww = csr_w[j];
        float2 v = ((const float2*)(x + (size_t)csr_src[j] * 128))[lane];
        ax = fmaxf(ax, v.x * ww); ay = fmaxf(ay, v.y * ww);
    }
    if (beg == end) { ax = 0.f; ay = 0.f; }
    ((float2*)(out + (size_t)gw * 128))[lane] = make_float2(ax, ay);
}

// ---- dual GEMM + bias + leaky: out = leaky(A1@W1 + A2@W2 + b) ----
__global__ __launch_bounds__(256) void dual_gemm_leaky(
    const float* __restrict__ A1, const float* __restrict__ A2,
    const float* __restrict__ W1, const float* __restrict__ W2,
    const float* __restrict__ bias, float* __restrict__ out,
    int M, int N, int K1, int K2) {
    constexpr int BM = 64, BN = 64, BK = 16;
    __shared__ float sA[BK][BM];
    __shared__ float sB[BK][BN];
    const int tid = threadIdx.x;
    const int bm0 = blockIdx.y * BM;
    const int bn0 = blockIdx.x * BN;
    const int K = K1 + K2;
    float acc[4][4] = {};
    const int ty = tid >> 4, tx = tid & 15;

    for (int k0 = 0; k0 < K; k0 += BK) {
        #pragma unroll
        for (int i = 0; i < (BM * BK) / 256; ++i) {
            int idx = tid + i * 256;
            int m = idx & (BM - 1);
            int k = idx >> 6;
            int gm = bm0 + m, gk = k0 + k;
            float v = 0.0f;
            if (gm < M)
                v = (gk < K1) ? A1[(size_t)gm * K1 + gk]
                              : A2[(size_t)gm * K2 + (gk - K1)];
            sA[k][m] = v;
        }
        #pragma unroll
        for (int i = 0; i < (BK * BN) / 256; ++i) {
            int idx = tid + i * 256;
            int n = idx & (BN - 1);
            int k = idx >> 6;
            int gk = k0 + k;
            float v = (gk < K1) ? W1[(size_t)gk * N + bn0 + n]
                                : W2[(size_t)(gk - K1) * N + bn0 + n];
            sB[k][n] = v;
        }
        __syncthreads();
        #pragma unroll
        for (int kk = 0; kk < BK; ++kk) {
            float a[4], b[4];
            #pragma unroll
            for (int i = 0; i < 4; ++i) a[i] = sA[kk][ty * 4 + i];
            #pragma unroll
            for (int j = 0; j < 4; ++j) b[j] = sB[kk][tx * 4 + j];
            #pragma unroll
            for (int i = 0; i < 4; ++i)
                #pragma unroll
                for (int j = 0; j < 4; ++j)
                    acc[i][j] = fmaf(a[i], b[j], acc[i][j]);
        }
        __syncthreads();
    }
    #pragma unroll
    for (int i = 0; i < 4; ++i) {
        int gm = bm0 + ty * 4 + i;
        if (gm >= M) continue;
        #pragma unroll
        for (int j = 0; j < 4; ++j) {
            int gn = bn0 + tx * 4 + j;
            float v = acc[i][j] + bias[gn];
            out[(size_t)gm * N + gn] = (v > 0.0f) ? v : 0.01f * v;
        }
    }
}

extern "C" void kernel_launch(void* const* d_in, const int* in_sizes, int n_in,
                              void* d_out, int out_size, void* d_ws, size_t ws_size,
                              hipStream_t stream) {
    const float* x_metric = (const float*)d_in[0];
    const float* x_alert  = (const float*)d_in[1];
    const float* w_corr   = (const float*)d_in[2];
    const float* w_cause  = (const float*)d_in[3];
    const int* src_corr   = (const int*)d_in[4];
    const int* dst_corr   = (const int*)d_in[5];
    const int* src_cause  = (const int*)d_in[6];
    const int* dst_cause  = (const int*)d_in[7];
    const float* Wr_c0 = (const float*)d_in[8];
    const float* br_c0 = (const float*)d_in[9];
    const float* Wo_c0 = (const float*)d_in[10];
    const float* Wr_k0 = (const float*)d_in[11];
    const float* br_k0 = (const float*)d_in[12];
    const float* Wo_k0 = (const float*)d_in[13];
    // d_in[14..16] (layer-1 corr weights) are dead: layer-1 metric update unused.
    const float* Wr_k1 = (const float*)d_in[17];
    const float* br_k1 = (const float*)d_in[18];
    const float* Wo_k1 = (const float*)d_in[19];

    // ---- workspace layout (4B elems), total 94.0 MB, heavily aliased ----
    float* ws = (float*)d_ws;
    float* xm0   = ws;                                 // [0, 12.8M) N_M x 128 (written by GEMM1)
    float* aggk0 = ws + 11520000;                      // N_A x 64, in xm0 tail (dead before GEMM1)
    // regB [12.8M, 15.36M): corr CSR, then xa0 after agg_sum
    int*   corr_rowptr = (int*)(ws + 12800000);        // N_M+1
    int*   corr_eids   = (int*)(ws + 12900016);        // E_C
    float* xa0         = ws + 12800000;                // N_A x 128 (after corr CSR dead)
    int*   cause_rowptr = (int*)(ws + 15360000);       // N_A+1
    int*   cause_src    = (int*)(ws + 15380016);       // E_K
    float* cause_w      = ws + 16180016;               // E_K
    int*   corr_cursor  = (int*)(ws + 16980016);       // N_M  } contiguous:
    int*   cause_cursor = (int*)(ws + 17080016);       // N_A  } one memset
    int*   corr_part    = (int*)(ws + 17100016);       // 64
    int*   cause_part   = (int*)(ws + 17100080);       // 64
    // regE [17100160, 23500160): aggm, then aggk1 after GEMM1
    float* aggm  = ws + 17100160;                      // N_M x 64
    float* aggk1 = ws + 17100160;                      // N_A x 128 (after aggm dead)

    const int corr_chunks  = (E_C + CH - 1) / CH;      // 782
    const int cause_chunks = (E_K + CH - 1) / CH;      // 391
    const int corr_P  = (N_M + CH - 1) / CH;           // 49
    const int cause_P = (N_A + CH - 1) / CH;           // 10

    // ---- CSR build ----
    hipMemsetAsync(corr_cursor, 0, (size_t)(N_M + N_A) * 4, stream);
    hist_part<<<corr_chunks * NXCD, 256, 0, stream>>>(dst_corr, corr_cursor, E_C, N_M / NXCD);
    hist_part<<<cause_chunks * NXCD, 256, 0, stream>>>(dst_cause, cause_cursor, E_K, N_A / NXCD);
    scan_p1<<<corr_P, 256, 0, stream>>>(corr_cursor, corr_part, N_M);
    scan_p1<<<cause_P, 256, 0, stream>>>(cause_cursor, cause_part, N_A);
    scan_p2<<<1, 64, 0, stream>>>(corr_part, corr_rowptr + N_M, corr_P);
    scan_p2<<<1, 64, 0, stream>>>(cause_part, cause_rowptr + N_A, cause_P);
    scan_p3<<<corr_P, 256, 0, stream>>>(corr_cursor, corr_part, corr_rowptr, corr_cursor, N_M);
    scan_p3<<<cause_P, 256, 0, stream>>>(cause_cursor, cause_part, cause_rowptr, cause_cursor, N_A);
    fill_eids_part<<<corr_chunks * NXCD, 256, 0, stream>>>(dst_corr, corr_cursor, corr_eids, E_C, N_M / NXCD);
    fill_pay_part<<<cause_chunks * NXCD, 256, 0, stream>>>(dst_cause, src_cause, w_cause,
                                                           cause_cursor, cause_src, cause_w,
                                                           E_K, N_A / NXCD);

    // ---- layer 0 aggregations ----
    agg_sum_d64<<<(N_M + 3) / 4, 256, 0, stream>>>(x_metric, w_corr, src_corr,
                                                   corr_rowptr, corr_eids, aggm, N_M);
    agg_max_d64_p<<<(N_A + 3) / 4, 256, 0, stream>>>(x_metric, cause_src, cause_w,
                                                     cause_rowptr, aggk0, N_A);

    // ---- layer 0 GEMMs (alert first: frees aggk0 before xm0 is written) ----
    {   // new_a = leaky(aggk0@Wr_k0 + x_alert@Wo_k0 + br_k0) -> xa0 (overlays dead corr CSR)
        dim3 grid(128 / 64, (N_A + 63) / 64);
        dual_gemm_leaky<<<grid, 256, 0, stream>>>(aggk0, x_alert, Wr_k0, Wo_k0, br_k0,
                                                  xa0, N_A, 128, 64, 64);
    }
    {   // new_m = leaky(aggm@Wr_c0 + x_metric@Wo_c0 + br_c0) -> xm0
        dim3 grid(128 / 64, (N_M + 63) / 64);
        dual_gemm_leaky<<<grid, 256, 0, stream>>>(aggm, x_metric, Wr_c0, Wo_c0, br_c0,
                                                  xm0, N_M, 128, 64, 64);
    }

    // ---- layer 1 (alert path only; metric update is dead code) ----
    agg_max_d128_p<<<(N_A + 3) / 4, 256, 0, stream>>>(xm0, cause_src, cause_w,
                                                      cause_rowptr, aggk1, N_A);
    {   // out = leaky(aggk1@Wr_k1 + xa0@Wo_k1 + br_k1) -> [N_A,256]
        dim3 grid(256 / 64, (N_A + 63) / 64);
        dual_gemm_leaky<<<grid, 256, 0, stream>>>(aggk1, xa0, Wr_k1, Wo_k1, br_k1,
                                                  (float*)d_out, N_A, 256, 128, 128);
    }
}

// Round 6
// 599.416 us; speedup vs baseline: 1.7883x; 1.1998x over previous
//
#include <hip/hip_runtime.h>

#define N_M 100000
#define N_A 20000
#define E_C 1600000
#define E_K 800000
#define CH 2048
#define NXCD 8

typedef __attribute__((ext_vector_type(8)))  short  short8_t;
typedef __attribute__((ext_vector_type(8)))  unsigned short ushort8_t;
typedef __attribute__((ext_vector_type(4)))  unsigned short ushort4_t;
typedef __attribute__((ext_vector_type(4)))  float  f32x4;

__device__ __forceinline__ unsigned short f2b(float f) {   // RNE f32->bf16
    unsigned u = __float_as_uint(f);
    return (unsigned short)((u + 0x7fffu + ((u >> 16) & 1u)) >> 16);
}
__device__ __forceinline__ float b2f(unsigned short h) {
    return __uint_as_float((unsigned)h << 16);
}

// =================== casts ===================
__global__ __launch_bounds__(256) void cast_f32_bf16(const float* __restrict__ in,
                                                     unsigned short* __restrict__ out, int n) {
    int i = (blockIdx.x * 256 + threadIdx.x) * 4;
    if (i >= n) return;
    float4 v = *(const float4*)(in + i);
    ushort4_t o; o.x = f2b(v.x); o.y = f2b(v.y); o.z = f2b(v.z); o.w = f2b(v.w);
    *(ushort4_t*)(out + i) = o;
}

// weights packed into one bf16 buffer at fixed offsets
__global__ __launch_bounds__(256) void cast_weights(
    const float* rc0, const float* oc0, const float* rk0, const float* ok0,
    const float* rk1, const float* ok1, unsigned short* __restrict__ wb) {
    int i = (blockIdx.x * 256 + threadIdx.x) * 4;
    if (i >= 98304) return;
    const float* src; int off;
    if      (i < 8192)  { src = rc0; off = 0; }
    else if (i < 16384) { src = oc0; off = 8192; }
    else if (i < 24576) { src = rk0; off = 16384; }
    else if (i < 32768) { src = ok0; off = 24576; }
    else if (i < 65536) { src = rk1; off = 32768; }
    else                { src = ok1; off = 65536; }
    float4 v = *(const float4*)(src + (i - off));
    ushort4_t o; o.x = f2b(v.x); o.y = f2b(v.y); o.z = f2b(v.z); o.w = f2b(v.w);
    *(ushort4_t*)(wb + i) = o;
}

// =================== XCD-partitioned CSR build ===================
__global__ __launch_bounds__(256) void hist_part(const int* __restrict__ dst,
                                                 int* __restrict__ deg,
                                                 int nE, int nodes_per_part) {
    int chunk = blockIdx.x >> 3, part = blockIdx.x & 7;
    int lo = part * nodes_per_part, hi = lo + nodes_per_part;
    int base = chunk * CH + threadIdx.x;
    #pragma unroll
    for (int k = 0; k < 8; ++k) {
        int e = base + k * 256;
        if (e < nE) {
            int d = dst[e];
            if (d >= lo && d < hi) atomicAdd(&deg[d], 1);
        }
    }
}

__global__ __launch_bounds__(256) void fill_pay_part(const int* __restrict__ dst,
                                                     const int* __restrict__ src,
                                                     const float* __restrict__ w,
                                                     int* __restrict__ cursor,
                                                     int* __restrict__ csr_src,
                                                     float* __restrict__ csr_w,
                                                     int nE, int nodes_per_part) {
    int chunk = blockIdx.x >> 3, part = blockIdx.x & 7;
    int lo = part * nodes_per_part, hi = lo + nodes_per_part;
    int base = chunk * CH + threadIdx.x;
    #pragma unroll
    for (int k = 0; k < 8; ++k) {
        int e = base + k * 256;
        if (e < nE) {
            int d = dst[e];
            if (d >= lo && d < hi) {
                int p = atomicAdd(&cursor[d], 1);
                csr_src[p] = src[e];
                csr_w[p]   = w[e];
            }
        }
    }
}

// =================== multi-block exclusive scan ===================
__global__ __launch_bounds__(256) void scan_p1(const int* __restrict__ deg,
                                               int* __restrict__ partial, int n) {
    __shared__ int red[256];
    int base = blockIdx.x * CH + threadIdx.x;
    int s = 0;
    #pragma unroll
    for (int k = 0; k < 8; ++k) { int i = base + k * 256; if (i < n) s += deg[i]; }
    red[threadIdx.x] = s; __syncthreads();
    for (int off = 128; off > 0; off >>= 1) {
        if (threadIdx.x < off) red[threadIdx.x] += red[threadIdx.x + off];
        __syncthreads();
    }
    if (threadIdx.x == 0) partial[blockIdx.x] = red[0];
}

__global__ __launch_bounds__(64) void scan_p2(int* __restrict__ partial,
                                              int* __restrict__ rowptr_end, int P) {
    int lane = threadIdx.x;
    int v = (lane < P) ? partial[lane] : 0;
    int incl = v;
    for (int off = 1; off < 64; off <<= 1) {
        int t = __shfl_up(incl, off);
        if (lane >= off) incl += t;
    }
    if (lane < P) partial[lane] = incl - v;
    if (lane == 63) *rowptr_end = incl;
}

__global__ __launch_bounds__(256) void scan_p3(const int* __restrict__ deg,
                                               const int* __restrict__ partial,
                                               int* __restrict__ rowptr,
                                               int* __restrict__ cursor, int n) {
    __shared__ int buf[256];
    int base = blockIdx.x * CH;
    int v[8]; int lsum = 0;
    #pragma unroll
    for (int k = 0; k < 8; ++k) {
        int i = base + threadIdx.x * 8 + k;
        v[k] = (i < n) ? deg[i] : 0; lsum += v[k];
    }
    buf[threadIdx.x] = lsum; __syncthreads();
    for (int off = 1; off < 256; off <<= 1) {
        int t = (threadIdx.x >= off) ? buf[threadIdx.x - off] : 0;
        __syncthreads(); buf[threadIdx.x] += t; __syncthreads();
    }
    int excl = buf[threadIdx.x] - lsum + partial[blockIdx.x];
    #pragma unroll
    for (int k = 0; k < 8; ++k) {
        int i = base + threadIdx.x * 8 + k;
        if (i < n) { rowptr[i] = excl; cursor[i] = excl; }
        excl += v[k];
    }
}

// =================== gather aggregations (bf16 features) ===================
__global__ __launch_bounds__(256) void agg_sum_d64_b(
    const unsigned short* __restrict__ x, const int* __restrict__ csr_src,
    const float* __restrict__ csr_w, const int* __restrict__ rowptr,
    unsigned short* __restrict__ out, int n) {
    int gw = blockIdx.x * 4 + (threadIdx.x >> 6);
    int lane = threadIdx.x & 63;
    if (gw >= n) return;
    int j = rowptr[gw], end = rowptr[gw + 1];
    float acc = 0.f;
    for (; j + 4 <= end; j += 4) {
        int s0 = csr_src[j], s1 = csr_src[j+1], s2 = csr_src[j+2], s3 = csr_src[j+3];
        float w0 = csr_w[j], w1 = csr_w[j+1], w2 = csr_w[j+2], w3 = csr_w[j+3];
        float v0 = b2f(x[(size_t)s0 * 64 + lane]);
        float v1 = b2f(x[(size_t)s1 * 64 + lane]);
        float v2 = b2f(x[(size_t)s2 * 64 + lane]);
        float v3 = b2f(x[(size_t)s3 * 64 + lane]);
        acc = fmaf(v0, w0, acc); acc = fmaf(v1, w1, acc);
        acc = fmaf(v2, w2, acc); acc = fmaf(v3, w3, acc);
    }
    for (; j < end; ++j)
        acc = fmaf(b2f(x[(size_t)csr_src[j] * 64 + lane]), csr_w[j], acc);
    out[(size_t)gw * 64 + lane] = f2b(acc);
}

__global__ __launch_bounds__(256) void agg_max_d64_b(
    const unsigned short* __restrict__ x, const int* __restrict__ csr_src,
    const float* __restrict__ csr_w, const int* __restrict__ rowptr,
    unsigned short* __restrict__ out, int n) {
    int gw = blockIdx.x * 4 + (threadIdx.x >> 6);
    int lane = threadIdx.x & 63;
    if (gw >= n) return;
    int beg = rowptr[gw], end = rowptr[gw + 1];
    float acc = -INFINITY;
    int j = beg;
    for (; j + 4 <= end; j += 4) {
        int s0 = csr_src[j], s1 = csr_src[j+1], s2 = csr_src[j+2], s3 = csr_src[j+3];
        float w0 = csr_w[j], w1 = csr_w[j+1], w2 = csr_w[j+2], w3 = csr_w[j+3];
        acc = fmaxf(acc, b2f(x[(size_t)s0 * 64 + lane]) * w0);
        acc = fmaxf(acc, b2f(x[(size_t)s1 * 64 + lane]) * w1);
        acc = fmaxf(acc, b2f(x[(size_t)s2 * 64 + lane]) * w2);
        acc = fmaxf(acc, b2f(x[(size_t)s3 * 64 + lane]) * w3);
    }
    for (; j < end; ++j)
        acc = fmaxf(acc, b2f(x[(size_t)csr_src[j] * 64 + lane]) * csr_w[j]);
    if (beg == end) acc = 0.f;
    out[(size_t)gw * 64 + lane] = f2b(acc);
}

__global__ __launch_bounds__(256) void agg_max_d128_b(
    const unsigned short* __restrict__ x, const int* __restrict__ csr_src,
    const float* __restrict__ csr_w, const int* __restrict__ rowptr,
    unsigned short* __restrict__ out, int n) {
    int gw = blockIdx.x * 4 + (threadIdx.x >> 6);
    int lane = threadIdx.x & 63;
    if (gw >= n) return;
    int beg = rowptr[gw], end = rowptr[gw + 1];
    float ax = -INFINITY, ay = -INFINITY;
    int j = beg;
    for (; j + 2 <= end; j += 2) {
        int s0 = csr_src[j], s1 = csr_src[j+1];
        float w0 = csr_w[j], w1 = csr_w[j+1];
        unsigned v0 = ((const unsigned*)(x + (size_t)s0 * 128))[lane];
        unsigned v1 = ((const unsigned*)(x + (size_t)s1 * 128))[lane];
        ax = fmaxf(ax, b2f((unsigned short)(v0 & 0xffff)) * w0);
        ay = fmaxf(ay, b2f((unsigned short)(v0 >> 16)) * w0);
        ax = fmaxf(ax, b2f((unsigned short)(v1 & 0xffff)) * w1);
        ay = fmaxf(ay, b2f((unsigned short)(v1 >> 16)) * w1);
    }
    for (; j < end; ++j) {
        float ww = csr_w[j];
        unsigned v = ((const unsigned*)(x + (size_t)csr_src[j] * 128))[lane];
        ax = fmaxf(ax, b2f((unsigned short)(v & 0xffff)) * ww);
        ay = fmaxf(ay, b2f((unsigned short)(v >> 16)) * ww);
    }
    if (beg == end) { ax = 0.f; ay = 0.f; }
    ((unsigned*)(out + (size_t)gw * 128))[lane] =
        (unsigned)f2b(ax) | ((unsigned)f2b(ay) << 16);
}

// =================== MFMA dual-GEMM + bias + leaky ===================
// out = leaky(A1@B1 + A2@B2 + bias). A row-major bf16 [M][K*]; B bf16 [K*][N].
// Block tile 128x64, 4 waves (2x2), K-step 32, B fully LDS-resident transposed.
// Frag maps (guide §3, m89-verified C/D): A row=lane&15,k=(lane>>4)*8+i;
// B col=lane&15, same k; C/D col=lane&15,row=(lane>>4)*4+i.
template <int K1, int K2, bool OBF>
__global__ __launch_bounds__(256) void dual_gemm_mfma(
    const unsigned short* __restrict__ A1, const unsigned short* __restrict__ A2,
    const unsigned short* __restrict__ B1, const unsigned short* __restrict__ B2,
    const float* __restrict__ bias, void* __restrict__ out, int M, int N) {
    constexpr int KTOT = K1 + K2;
    constexpr int LB = KTOT + 8;                     // sBT row stride (bf16)
    __shared__ __align__(16) unsigned short sA[128 * 40];
    __shared__ __align__(16) unsigned short sBT[64 * LB];

    const int tid = threadIdx.x;
    const int lane = tid & 63, wid = tid >> 6;
    const int wm = wid >> 1, wn = wid & 1;
    const int bm0 = blockIdx.y * 128, n0 = blockIdx.x * 64;

    // ---- load B block transposed into LDS ----
    for (int idx = tid; idx < KTOT * 64; idx += 256) {
        int k = idx >> 6, n = idx & 63;
        unsigned short v = (k < K1) ? B1[k * N + n0 + n] : B2[(k - K1) * N + n0 + n];
        sBT[n * LB + k] = v;
    }

    f32x4 acc[4][2];
    #pragma unroll
    for (int i = 0; i < 4; ++i)
        #pragma unroll
        for (int j = 0; j < 2; ++j)
            acc[i][j] = (f32x4){0.f, 0.f, 0.f, 0.f};

    const int kk = (lane >> 4) * 8;
    const int l15 = lane & 15;

    for (int k0 = 0; k0 < KTOT; k0 += 32) {
        __syncthreads();   // sA safe to overwrite (also covers B-phase on iter 0)
        #pragma unroll
        for (int i = 0; i < 2; ++i) {
            int v = tid + i * 256;              // 512 vectors of 8 bf16
            int row = v >> 2, kv = (v & 3) * 8;
            int gm = bm0 + row, gk = k0 + kv;
            ushort8_t val = (ushort8_t)0;
            if (gm < M) {
                const unsigned short* src = (gk < K1)
                    ? (A1 + (size_t)gm * K1 + gk)
                    : (A2 + (size_t)gm * K2 + (gk - K1));
                val = *(const ushort8_t*)src;
            }
            *(ushort8_t*)(sA + row * 40 + kv) = val;
        }
        __syncthreads();

        short8_t bfr[2];
        #pragma unroll
        for (int nf = 0; nf < 2; ++nf)
            bfr[nf] = *(const short8_t*)(sBT + (wn * 32 + nf * 16 + l15) * LB + k0 + kk);
        #pragma unroll
        for (int mf = 0; mf < 4; ++mf) {
            short8_t a = *(const short8_t*)(sA + (wm * 64 + mf * 16 + l15) * 40 + kk);
            acc[mf][0] = __builtin_amdgcn_mfma_f32_16x16x32_bf16(a, bfr[0], acc[mf][0], 0, 0, 0);
            acc[mf][1] = __builtin_amdgcn_mfma_f32_16x16x32_bf16(a, bfr[1], acc[mf][1], 0, 0, 0);
        }
    }

    // ---- epilogue ----
    #pragma unroll
    for (int nf = 0; nf < 2; ++nf) {
        int col = n0 + wn * 32 + nf * 16 + l15;
        float bcol = bias[col];
        #pragma unroll
        for (int mf = 0; mf < 4; ++mf) {
            int rowb = bm0 + wm * 64 + mf * 16 + (lane >> 4) * 4;
            #pragma unroll
            for (int i = 0; i < 4; ++i) {
                int r = rowb + i;
                if (r >= M) continue;
                float v = acc[mf][nf][i] + bcol;
                v = (v > 0.f) ? v : 0.01f * v;
                if (OBF) ((unsigned short*)out)[(size_t)r * N + col] = f2b(v);
                else     ((float*)out)[(size_t)r * N + col] = v;
            }
        }
    }
}

extern "C" void kernel_launch(void* const* d_in, const int* in_sizes, int n_in,
                              void* d_out, int out_size, void* d_ws, size_t ws_size,
                              hipStream_t stream) {
    const float* x_metric = (const float*)d_in[0];
    const float* x_alert  = (const float*)d_in[1];
    const float* w_corr   = (const float*)d_in[2];
    const float* w_cause  = (const float*)d_in[3];
    const int* src_corr   = (const int*)d_in[4];
    const int* dst_corr   = (const int*)d_in[5];
    const int* src_cause  = (const int*)d_in[6];
    const int* dst_cause  = (const int*)d_in[7];
    const float* Wr_c0 = (const float*)d_in[8];
    const float* br_c0 = (const float*)d_in[9];
    const float* Wo_c0 = (const float*)d_in[10];
    const float* Wr_k0 = (const float*)d_in[11];
    const float* br_k0 = (const float*)d_in[12];
    const float* Wo_k0 = (const float*)d_in[13];
    // d_in[14..16] dead (layer-1 metric update unused)
    const float* Wr_k1 = (const float*)d_in[17];
    const float* br_k1 = (const float*)d_in[18];
    const float* Wo_k1 = (const float*)d_in[19];

    // ---- workspace (float units), total ~87 MB, no aliasing ----
    float* ws = (float*)d_ws;
    unsigned short* xh_m = (unsigned short*)(ws);                 // N_M x 64 bf16
    unsigned short* xh_a = (unsigned short*)(ws + 3200000);       // N_A x 64 bf16
    unsigned short* wb   = (unsigned short*)(ws + 3840000);       // 98304 bf16 weights
    int*   corr_rowptr  = (int*)(ws + 3900000);                   // N_M+1
    int*   corr_src     = (int*)(ws + 4000064);                   // E_C
    float* corr_w       = (ws + 5600064);                         // E_C
    int*   cause_rowptr = (int*)(ws + 7200064);                   // N_A+1
    int*   cause_src    = (int*)(ws + 7220128);                   // E_K
    float* cause_w      = (ws + 8020128);                         // E_K
    int*   corr_cursor  = (int*)(ws + 8820128);                   // N_M }
    int*   cause_cursor = (int*)(ws + 8920128);                   // N_A } one memset
    int*   corr_part    = (int*)(ws + 8940128);                   // 64
    int*   cause_part   = (int*)(ws + 8940192);                   // 64
    unsigned short* aggm  = (unsigned short*)(ws + 9000000);      // N_M x 64 bf16
    unsigned short* aggk0 = (unsigned short*)(ws + 12200000);     // N_A x 64 bf16
    unsigned short* xm0h  = (unsigned short*)(ws + 12840000);     // N_M x 128 bf16
    unsigned short* xa0h  = (unsigned short*)(ws + 19240000);     // N_A x 128 bf16
    unsigned short* aggk1 = (unsigned short*)(ws + 20520000);     // N_A x 128 bf16

    const unsigned short* Wb_rc0 = wb;
    const unsigned short* Wb_oc0 = wb + 8192;
    const unsigned short* Wb_rk0 = wb + 16384;
    const unsigned short* Wb_ok0 = wb + 24576;
    const unsigned short* Wb_rk1 = wb + 32768;
    const unsigned short* Wb_ok1 = wb + 65536;

    const int corr_chunks  = (E_C + CH - 1) / CH;
    const int cause_chunks = (E_K + CH - 1) / CH;
    const int corr_P  = (N_M + CH - 1) / CH;    // 49
    const int cause_P = (N_A + CH - 1) / CH;    // 10

    // ---- casts (independent of CSR build) ----
    cast_f32_bf16<<<(N_M * 64 / 4 + 255) / 256, 256, 0, stream>>>(x_metric, xh_m, N_M * 64);
    cast_f32_bf16<<<(N_A * 64 / 4 + 255) / 256, 256, 0, stream>>>(x_alert, xh_a, N_A * 64);
    cast_weights<<<96, 256, 0, stream>>>(Wr_c0, Wo_c0, Wr_k0, Wo_k0, Wr_k1, Wo_k1, wb);

    // ---- CSR build (payload CSR for both edge types) ----
    hipMemsetAsync(corr_cursor, 0, (size_t)(N_M + N_A) * 4, stream);
    hist_part<<<corr_chunks * NXCD, 256, 0, stream>>>(dst_corr, corr_cursor, E_C, N_M / NXCD);
    hist_part<<<cause_chunks * NXCD, 256, 0, stream>>>(dst_cause, cause_cursor, E_K, N_A / NXCD);
    scan_p1<<<corr_P, 256, 0, stream>>>(corr_cursor, corr_part, N_M);
    scan_p1<<<cause_P, 256, 0, stream>>>(cause_cursor, cause_part, N_A);
    scan_p2<<<1, 64, 0, stream>>>(corr_part, corr_rowptr + N_M, corr_P);
    scan_p2<<<1, 64, 0, stream>>>(cause_part, cause_rowptr + N_A, cause_P);
    scan_p3<<<corr_P, 256, 0, stream>>>(corr_cursor, corr_part, corr_rowptr, corr_cursor, N_M);
    scan_p3<<<cause_P, 256, 0, stream>>>(cause_cursor, cause_part, cause_rowptr, cause_cursor, N_A);
    fill_pay_part<<<corr_chunks * NXCD, 256, 0, stream>>>(dst_corr, src_corr, w_corr,
                                                          corr_cursor, corr_src, corr_w,
                                                          E_C, N_M / NXCD);
    fill_pay_part<<<cause_chunks * NXCD, 256, 0, stream>>>(dst_cause, src_cause, w_cause,
                                                           cause_cursor, cause_src, cause_w,
                                                           E_K, N_A / NXCD);

    // ---- layer 0 aggregations ----
    agg_sum_d64_b<<<(N_M + 3) / 4, 256, 0, stream>>>(xh_m, corr_src, corr_w,
                                                     corr_rowptr, aggm, N_M);
    agg_max_d64_b<<<(N_A + 3) / 4, 256, 0, stream>>>(xh_m, cause_src, cause_w,
                                                     cause_rowptr, aggk0, N_A);

    // ---- layer 0 GEMMs (MFMA) ----
    {   dim3 grid(128 / 64, (N_A + 127) / 128);   // xa0 = leaky(aggk0@Wr_k0 + xh_a@Wo_k0 + b)
        dual_gemm_mfma<64, 64, true><<<grid, 256, 0, stream>>>(
            aggk0, xh_a, Wb_rk0, Wb_ok0, br_k0, xa0h, N_A, 128);
    }
    {   dim3 grid(128 / 64, (N_M + 127) / 128);   // xm0 = leaky(aggm@Wr_c0 + xh_m@Wo_c0 + b)
        dual_gemm_mfma<64, 64, true><<<grid, 256, 0, stream>>>(
            aggm, xh_m, Wb_rc0, Wb_oc0, br_c0, xm0h, N_M, 128);
    }

    // ---- layer 1 (alert path only) ----
    agg_max_d128_b<<<(N_A + 3) / 4, 256, 0, stream>>>(xm0h, cause_src, cause_w,
                                                      cause_rowptr, aggk1, N_A);
    {   dim3 grid(256 / 64, (N_A + 127) / 128);   // out = leaky(aggk1@Wr_k1 + xa0@Wo_k1 + b)
        dual_gemm_mfma<128, 128, false><<<grid, 256, 0, stream>>>(
            aggk1, xa0h, Wb_rk1, Wb_ok1, br_k1, (float*)d_out, N_A, 256);
    }
}

// Round 7
// 589.926 us; speedup vs baseline: 1.8170x; 1.0161x over previous
//
#include <hip/hip_runtime.h>

#define N_M 100000
#define N_A 20000
#define E_C 1600000
#define E_K 800000
#define CH 2048
#define NXCD 8

typedef __attribute__((ext_vector_type(8)))  short  short8_t;
typedef __attribute__((ext_vector_type(8)))  unsigned short ushort8_t;
typedef __attribute__((ext_vector_type(4)))  unsigned short ushort4_t;
typedef __attribute__((ext_vector_type(4)))  float  f32x4;

__device__ __forceinline__ unsigned short f2b(float f) {   // RNE f32->bf16
    unsigned u = __float_as_uint(f);
    return (unsigned short)((u + 0x7fffu + ((u >> 16) & 1u)) >> 16);
}
__device__ __forceinline__ float b2f(unsigned short h) {
    return __uint_as_float((unsigned)h << 16);
}

// =================== casts ===================
__global__ __launch_bounds__(256) void cast_f32_bf16(const float* __restrict__ in,
                                                     unsigned short* __restrict__ out, int n) {
    int i = (blockIdx.x * 256 + threadIdx.x) * 4;
    if (i >= n) return;
    float4 v = *(const float4*)(in + i);
    ushort4_t o; o.x = f2b(v.x); o.y = f2b(v.y); o.z = f2b(v.z); o.w = f2b(v.w);
    *(ushort4_t*)(out + i) = o;
}

__global__ __launch_bounds__(256) void cast_weights(
    const float* rc0, const float* oc0, const float* rk0, const float* ok0,
    const float* rk1, const float* ok1, unsigned short* __restrict__ wb) {
    int i = (blockIdx.x * 256 + threadIdx.x) * 4;
    if (i >= 98304) return;
    const float* src; int off;
    if      (i < 8192)  { src = rc0; off = 0; }
    else if (i < 16384) { src = oc0; off = 8192; }
    else if (i < 24576) { src = rk0; off = 16384; }
    else if (i < 32768) { src = ok0; off = 24576; }
    else if (i < 65536) { src = rk1; off = 32768; }
    else                { src = ok1; off = 65536; }
    float4 v = *(const float4*)(src + (i - off));
    ushort4_t o; o.x = f2b(v.x); o.y = f2b(v.y); o.z = f2b(v.z); o.w = f2b(v.w);
    *(ushort4_t*)(wb + i) = o;
}

// =================== XCD-partitioned CSR build ===================
// block b: chunk=b>>3, part=b&7. blockIdx round-robins across XCDs, so part p
// stays on XCD p: cursor atomics + payload writes are L2-local. Streaming
// reads use non-temporal loads (evict-first) to protect the write lines.

__global__ __launch_bounds__(256) void hist_part(const int* __restrict__ dst,
                                                 int* __restrict__ deg,
                                                 int nE, int nodes_per_part) {
    int chunk = blockIdx.x >> 3, part = blockIdx.x & 7;
    int lo = part * nodes_per_part, hi = lo + nodes_per_part;
    int base = chunk * CH + threadIdx.x;
    #pragma unroll
    for (int k = 0; k < 8; ++k) {
        int e = base + k * 256;
        if (e < nE) {
            int d = __builtin_nontemporal_load(dst + e);
            if (d >= lo && d < hi) atomicAdd(&deg[d], 1);
        }
    }
}

__global__ __launch_bounds__(256) void fill_pay_part(const int* __restrict__ dst,
                                                     const int* __restrict__ src,
                                                     const float* __restrict__ w,
                                                     int* __restrict__ cursor,
                                                     int2* __restrict__ csr_sw,
                                                     int nE, int nodes_per_part) {
    int chunk = blockIdx.x >> 3, part = blockIdx.x & 7;
    int lo = part * nodes_per_part, hi = lo + nodes_per_part;
    int base = chunk * CH + threadIdx.x;
    #pragma unroll
    for (int k = 0; k < 8; ++k) {
        int e = base + k * 256;
        if (e < nE) {
            int d = __builtin_nontemporal_load(dst + e);
            if (d >= lo && d < hi) {
                int p = atomicAdd(&cursor[d], 1);
                int2 sw;
                sw.x = __builtin_nontemporal_load(src + e);
                sw.y = __float_as_int(__builtin_nontemporal_load(w + e));
                csr_sw[p] = sw;
            }
        }
    }
}

// =================== multi-block exclusive scan ===================
__global__ __launch_bounds__(256) void scan_p1(const int* __restrict__ deg,
                                               int* __restrict__ partial, int n) {
    __shared__ int red[256];
    int base = blockIdx.x * CH + threadIdx.x;
    int s = 0;
    #pragma unroll
    for (int k = 0; k < 8; ++k) { int i = base + k * 256; if (i < n) s += deg[i]; }
    red[threadIdx.x] = s; __syncthreads();
    for (int off = 128; off > 0; off >>= 1) {
        if (threadIdx.x < off) red[threadIdx.x] += red[threadIdx.x + off];
        __syncthreads();
    }
    if (threadIdx.x == 0) partial[blockIdx.x] = red[0];
}

__global__ __launch_bounds__(64) void scan_p2(int* __restrict__ partial,
                                              int* __restrict__ rowptr_end, int P) {
    int lane = threadIdx.x;
    int v = (lane < P) ? partial[lane] : 0;
    int incl = v;
    for (int off = 1; off < 64; off <<= 1) {
        int t = __shfl_up(incl, off);
        if (lane >= off) incl += t;
    }
    if (lane < P) partial[lane] = incl - v;
    if (lane == 63) *rowptr_end = incl;
}

__global__ __launch_bounds__(256) void scan_p3(const int* __restrict__ deg,
                                               const int* __restrict__ partial,
                                               int* __restrict__ rowptr,
                                               int* __restrict__ cursor, int n) {
    __shared__ int buf[256];
    int base = blockIdx.x * CH;
    int v[8]; int lsum = 0;
    #pragma unroll
    for (int k = 0; k < 8; ++k) {
        int i = base + threadIdx.x * 8 + k;
        v[k] = (i < n) ? deg[i] : 0; lsum += v[k];
    }
    buf[threadIdx.x] = lsum; __syncthreads();
    for (int off = 1; off < 256; off <<= 1) {
        int t = (threadIdx.x >= off) ? buf[threadIdx.x - off] : 0;
        __syncthreads(); buf[threadIdx.x] += t; __syncthreads();
    }
    int excl = buf[threadIdx.x] - lsum + partial[blockIdx.x];
    #pragma unroll
    for (int k = 0; k < 8; ++k) {
        int i = base + threadIdx.x * 8 + k;
        if (i < n) { rowptr[i] = excl; cursor[i] = excl; }
        excl += v[k];
    }
}

// =================== gather aggregations (bf16 features) ===================
__global__ __launch_bounds__(256) void agg_sum_d64_b(
    const unsigned short* __restrict__ x, const int2* __restrict__ csr_sw,
    const int* __restrict__ rowptr, unsigned short* __restrict__ out, int n) {
    int gw = blockIdx.x * 4 + (threadIdx.x >> 6);
    int lane = threadIdx.x & 63;
    if (gw >= n) return;
    int j = rowptr[gw], end = rowptr[gw + 1];
    float acc = 0.f;
    for (; j + 4 <= end; j += 4) {
        int2 e0 = csr_sw[j], e1 = csr_sw[j+1], e2 = csr_sw[j+2], e3 = csr_sw[j+3];
        float v0 = b2f(x[(size_t)e0.x * 64 + lane]);
        float v1 = b2f(x[(size_t)e1.x * 64 + lane]);
        float v2 = b2f(x[(size_t)e2.x * 64 + lane]);
        float v3 = b2f(x[(size_t)e3.x * 64 + lane]);
        acc = fmaf(v0, __int_as_float(e0.y), acc);
        acc = fmaf(v1, __int_as_float(e1.y), acc);
        acc = fmaf(v2, __int_as_float(e2.y), acc);
        acc = fmaf(v3, __int_as_float(e3.y), acc);
    }
    for (; j < end; ++j) {
        int2 e = csr_sw[j];
        acc = fmaf(b2f(x[(size_t)e.x * 64 + lane]), __int_as_float(e.y), acc);
    }
    out[(size_t)gw * 64 + lane] = f2b(acc);
}

__global__ __launch_bounds__(256) void agg_max_d64_b(
    const unsigned short* __restrict__ x, const int2* __restrict__ csr_sw,
    const int* __restrict__ rowptr, unsigned short* __restrict__ out, int n) {
    int gw = blockIdx.x * 4 + (threadIdx.x >> 6);
    int lane = threadIdx.x & 63;
    if (gw >= n) return;
    int beg = rowptr[gw], end = rowptr[gw + 1];
    float acc = -INFINITY;
    int j = beg;
    for (; j + 4 <= end; j += 4) {
        int2 e0 = csr_sw[j], e1 = csr_sw[j+1], e2 = csr_sw[j+2], e3 = csr_sw[j+3];
        acc = fmaxf(acc, b2f(x[(size_t)e0.x * 64 + lane]) * __int_as_float(e0.y));
        acc = fmaxf(acc, b2f(x[(size_t)e1.x * 64 + lane]) * __int_as_float(e1.y));
        acc = fmaxf(acc, b2f(x[(size_t)e2.x * 64 + lane]) * __int_as_float(e2.y));
        acc = fmaxf(acc, b2f(x[(size_t)e3.x * 64 + lane]) * __int_as_float(e3.y));
    }
    for (; j < end; ++j) {
        int2 e = csr_sw[j];
        acc = fmaxf(acc, b2f(x[(size_t)e.x * 64 + lane]) * __int_as_float(e.y));
    }
    if (beg == end) acc = 0.f;
    out[(size_t)gw * 64 + lane] = f2b(acc);
}

__global__ __launch_bounds__(256) void agg_max_d128_b(
    const unsigned short* __restrict__ x, const int2* __restrict__ csr_sw,
    const int* __restrict__ rowptr, unsigned short* __restrict__ out, int n) {
    int gw = blockIdx.x * 4 + (threadIdx.x >> 6);
    int lane = threadIdx.x & 63;
    if (gw >= n) return;
    int beg = rowptr[gw], end = rowptr[gw + 1];
    float ax = -INFINITY, ay = -INFINITY;
    int j = beg;
    for (; j + 2 <= end; j += 2) {
        int2 e0 = csr_sw[j], e1 = csr_sw[j+1];
        float w0 = __int_as_float(e0.y), w1 = __int_as_float(e1.y);
        unsigned v0 = ((const unsigned*)(x + (size_t)e0.x * 128))[lane];
        unsigned v1 = ((const unsigned*)(x + (size_t)e1.x * 128))[lane];
        ax = fmaxf(ax, b2f((unsigned short)(v0 & 0xffff)) * w0);
        ay = fmaxf(ay, b2f((unsigned short)(v0 >> 16)) * w0);
        ax = fmaxf(ax, b2f((unsigned short)(v1 & 0xffff)) * w1);
        ay = fmaxf(ay, b2f((unsigned short)(v1 >> 16)) * w1);
    }
    for (; j < end; ++j) {
        int2 e = csr_sw[j];
        float ww = __int_as_float(e.y);
        unsigned v = ((const unsigned*)(x + (size_t)e.x * 128))[lane];
        ax = fmaxf(ax, b2f((unsigned short)(v & 0xffff)) * ww);
        ay = fmaxf(ay, b2f((unsigned short)(v >> 16)) * ww);
    }
    if (beg == end) { ax = 0.f; ay = 0.f; }
    ((unsigned*)(out + (size_t)gw * 128))[lane] =
        (unsigned)f2b(ax) | ((unsigned)f2b(ay) << 16);
}

// =================== MFMA dual-GEMM + bias + leaky ===================
template <int K1, int K2, bool OBF>
__global__ __launch_bounds__(256) void dual_gemm_mfma(
    const unsigned short* __restrict__ A1, const unsigned short* __restrict__ A2,
    const unsigned short* __restrict__ B1, const unsigned short* __restrict__ B2,
    const float* __restrict__ bias, void* __restrict__ out, int M, int N) {
    constexpr int KTOT = K1 + K2;
    constexpr int LB = KTOT + 8;
    __shared__ __align__(16) unsigned short sA[128 * 40];
    __shared__ __align__(16) unsigned short sBT[64 * LB];

    const int tid = threadIdx.x;
    const int lane = tid & 63, wid = tid >> 6;
    const int wm = wid >> 1, wn = wid & 1;
    const int bm0 = blockIdx.y * 128, n0 = blockIdx.x * 64;

    for (int idx = tid; idx < KTOT * 64; idx += 256) {
        int k = idx >> 6, n = idx & 63;
        unsigned short v = (k < K1) ? B1[k * N + n0 + n] : B2[(k - K1) * N + n0 + n];
        sBT[n * LB + k] = v;
    }

    f32x4 acc[4][2];
    #pragma unroll
    for (int i = 0; i < 4; ++i)
        #pragma unroll
        for (int j = 0; j < 2; ++j)
            acc[i][j] = (f32x4){0.f, 0.f, 0.f, 0.f};

    const int kk = (lane >> 4) * 8;
    const int l15 = lane & 15;

    for (int k0 = 0; k0 < KTOT; k0 += 32) {
        __syncthreads();
        #pragma unroll
        for (int i = 0; i < 2; ++i) {
            int v = tid + i * 256;
            int row = v >> 2, kv = (v & 3) * 8;
            int gm = bm0 + row, gk = k0 + kv;
            ushort8_t val = (ushort8_t)0;
            if (gm < M) {
                const unsigned short* src = (gk < K1)
                    ? (A1 + (size_t)gm * K1 + gk)
                    : (A2 + (size_t)gm * K2 + (gk - K1));
                val = *(const ushort8_t*)src;
            }
            *(ushort8_t*)(sA + row * 40 + kv) = val;
        }
        __syncthreads();

        short8_t bfr[2];
        #pragma unroll
        for (int nf = 0; nf < 2; ++nf)
            bfr[nf] = *(const short8_t*)(sBT + (wn * 32 + nf * 16 + l15) * LB + k0 + kk);
        #pragma unroll
        for (int mf = 0; mf < 4; ++mf) {
            short8_t a = *(const short8_t*)(sA + (wm * 64 + mf * 16 + l15) * 40 + kk);
            acc[mf][0] = __builtin_amdgcn_mfma_f32_16x16x32_bf16(a, bfr[0], acc[mf][0], 0, 0, 0);
            acc[mf][1] = __builtin_amdgcn_mfma_f32_16x16x32_bf16(a, bfr[1], acc[mf][1], 0, 0, 0);
        }
    }

    #pragma unroll
    for (int nf = 0; nf < 2; ++nf) {
        int col = n0 + wn * 32 + nf * 16 + l15;
        float bcol = bias[col];
        #pragma unroll
        for (int mf = 0; mf < 4; ++mf) {
            int rowb = bm0 + wm * 64 + mf * 16 + (lane >> 4) * 4;
            #pragma unroll
            for (int i = 0; i < 4; ++i) {
                int r = rowb + i;
                if (r >= M) continue;
                float v = acc[mf][nf][i] + bcol;
                v = (v > 0.f) ? v : 0.01f * v;
                if (OBF) ((unsigned short*)out)[(size_t)r * N + col] = f2b(v);
                else     ((float*)out)[(size_t)r * N + col] = v;
            }
        }
    }
}

extern "C" void kernel_launch(void* const* d_in, const int* in_sizes, int n_in,
                              void* d_out, int out_size, void* d_ws, size_t ws_size,
                              hipStream_t stream) {
    const float* x_metric = (const float*)d_in[0];
    const float* x_alert  = (const float*)d_in[1];
    const float* w_corr   = (const float*)d_in[2];
    const float* w_cause  = (const float*)d_in[3];
    const int* src_corr   = (const int*)d_in[4];
    const int* dst_corr   = (const int*)d_in[5];
    const int* src_cause  = (const int*)d_in[6];
    const int* dst_cause  = (const int*)d_in[7];
    const float* Wr_c0 = (const float*)d_in[8];
    const float* br_c0 = (const float*)d_in[9];
    const float* Wo_c0 = (const float*)d_in[10];
    const float* Wr_k0 = (const float*)d_in[11];
    const float* br_k0 = (const float*)d_in[12];
    const float* Wo_k0 = (const float*)d_in[13];
    // d_in[14..16] dead (layer-1 metric update unused)
    const float* Wr_k1 = (const float*)d_in[17];
    const float* br_k1 = (const float*)d_in[18];
    const float* Wo_k1 = (const float*)d_in[19];

    // ---- workspace (float units), ~87 MB ----
    float* ws = (float*)d_ws;
    unsigned short* xh_m = (unsigned short*)(ws);                 // N_M x 64 bf16
    unsigned short* xh_a = (unsigned short*)(ws + 3200000);       // N_A x 64 bf16
    unsigned short* wb   = (unsigned short*)(ws + 3840000);       // 98304 bf16
    int*  corr_rowptr  = (int*)(ws + 3900000);                    // N_M+1
    int2* corr_sw      = (int2*)(ws + 4000064);                   // E_C (8B each)
    int*  cause_rowptr = (int*)(ws + 7200064);                    // N_A+1
    int2* cause_sw     = (int2*)(ws + 7220128);                   // E_K
    int*  corr_cursor  = (int*)(ws + 8820128);                    // N_M }
    int*  cause_cursor = (int*)(ws + 8920128);                    // N_A } one memset
    int*  corr_part    = (int*)(ws + 8940128);                    // 64
    int*  cause_part   = (int*)(ws + 8940192);                    // 64
    unsigned short* aggm  = (unsigned short*)(ws + 9000000);      // N_M x 64 bf16
    unsigned short* aggk0 = (unsigned short*)(ws + 12200000);     // N_A x 64 bf16
    unsigned short* xm0h  = (unsigned short*)(ws + 12840000);     // N_M x 128 bf16
    unsigned short* xa0h  = (unsigned short*)(ws + 19240000);     // N_A x 128 bf16
    unsigned short* aggk1 = (unsigned short*)(ws + 20520000);     // N_A x 128 bf16

    const unsigned short* Wb_rc0 = wb;
    const unsigned short* Wb_oc0 = wb + 8192;
    const unsigned short* Wb_rk0 = wb + 16384;
    const unsigned short* Wb_ok0 = wb + 24576;
    const unsigned short* Wb_rk1 = wb + 32768;
    const unsigned short* Wb_ok1 = wb + 65536;

    const int corr_chunks  = (E_C + CH - 1) / CH;
    const int cause_chunks = (E_K + CH - 1) / CH;
    const int corr_P  = (N_M + CH - 1) / CH;    // 49
    const int cause_P = (N_A + CH - 1) / CH;    // 10

    // ---- casts ----
    cast_f32_bf16<<<(N_M * 64 / 4 + 255) / 256, 256, 0, stream>>>(x_metric, xh_m, N_M * 64);
    cast_f32_bf16<<<(N_A * 64 / 4 + 255) / 256, 256, 0, stream>>>(x_alert, xh_a, N_A * 64);
    cast_weights<<<96, 256, 0, stream>>>(Wr_c0, Wo_c0, Wr_k0, Wo_k0, Wr_k1, Wo_k1, wb);

    // ---- CSR build (combined int2 payload; nt streaming reads) ----
    hipMemsetAsync(corr_cursor, 0, (size_t)(N_M + N_A) * 4, stream);
    hist_part<<<corr_chunks * NXCD, 256, 0, stream>>>(dst_corr, corr_cursor, E_C, N_M / NXCD);
    hist_part<<<cause_chunks * NXCD, 256, 0, stream>>>(dst_cause, cause_cursor, E_K, N_A / NXCD);
    scan_p1<<<corr_P, 256, 0, stream>>>(corr_cursor, corr_part, N_M);
    scan_p1<<<cause_P, 256, 0, stream>>>(cause_cursor, cause_part, N_A);
    scan_p2<<<1, 64, 0, stream>>>(corr_part, corr_rowptr + N_M, corr_P);
    scan_p2<<<1, 64, 0, stream>>>(cause_part, cause_rowptr + N_A, cause_P);
    scan_p3<<<corr_P, 256, 0, stream>>>(corr_cursor, corr_part, corr_rowptr, corr_cursor, N_M);
    scan_p3<<<cause_P, 256, 0, stream>>>(cause_cursor, cause_part, cause_rowptr, cause_cursor, N_A);
    fill_pay_part<<<corr_chunks * NXCD, 256, 0, stream>>>(dst_corr, src_corr, w_corr,
                                                          corr_cursor, corr_sw, E_C, N_M / NXCD);
    fill_pay_part<<<cause_chunks * NXCD, 256, 0, stream>>>(dst_cause, src_cause, w_cause,
                                                           cause_cursor, cause_sw, E_K, N_A / NXCD);

    // ---- layer 0 aggregations ----
    agg_sum_d64_b<<<(N_M + 3) / 4, 256, 0, stream>>>(xh_m, corr_sw, corr_rowptr, aggm, N_M);
    agg_max_d64_b<<<(N_A + 3) / 4, 256, 0, stream>>>(xh_m, cause_sw, cause_rowptr, aggk0, N_A);

    // ---- layer 0 GEMMs (MFMA) ----
    {   dim3 grid(128 / 64, (N_A + 127) / 128);
        dual_gemm_mfma<64, 64, true><<<grid, 256, 0, stream>>>(
            aggk0, xh_a, Wb_rk0, Wb_ok0, br_k0, xa0h, N_A, 128);
    }
    {   dim3 grid(128 / 64, (N_M + 127) / 128);
        dual_gemm_mfma<64, 64, true><<<grid, 256, 0, stream>>>(
            aggm, xh_m, Wb_rc0, Wb_oc0, br_c0, xm0h, N_M, 128);
    }

    // ---- layer 1 (alert path only) ----
    agg_max_d128_b<<<(N_A + 3) / 4, 256, 0, stream>>>(xm0h, cause_sw, cause_rowptr, aggk1, N_A);
    {   dim3 grid(256 / 64, (N_A + 127) / 128);
        dual_gemm_mfma<128, 128, false><<<grid, 256, 0, stream>>>(
            aggk1, xa0h, Wb_rk1, Wb_ok1, br_k1, (float*)d_out, N_A, 256);
    }
}